// Round 1
// baseline (156.192 us; speedup 1.0000x reference)
//
#include <hip/hip_runtime.h>
#include <hip/hip_bf16.h>

// CondConv: B=32, CIN=128, COUT=256, K=3, E=8, H=W=64 -> out [32,256,62,62] fp32
// Pipeline: pool -> routing(softmax) -> combine(bf16 cw, (ky,kx)-major) ->
//           NCHW->NHWC bf16 cast -> implicit-GEMM MFMA conv.

#define CC_B    32
#define CC_CIN  128
#define CC_COUT 256
#define CC_E    8
#define CC_H    64
#define CC_W    64
#define CC_OH   62
#define CC_OW   62
#define CC_NP   3844   // 62*62

typedef __attribute__((ext_vector_type(8))) short bf16x8;   // 8 bf16 (4 VGPRs), per guide §3
typedef __attribute__((ext_vector_type(4))) float f32x4;

// ---------------------------------------------------------------- pool ------
__global__ void cc_pool(const float* __restrict__ x, float* __restrict__ pooled) {
    const int bc = blockIdx.x;                 // b*128 + cin, 4096 blocks
    const float* src = x + (size_t)bc * 4096;
    const int t = threadIdx.x;                 // 256 threads
    float s = 0.f;
#pragma unroll
    for (int i = 0; i < 16; ++i) s += src[t + i * 256];
#pragma unroll
    for (int off = 32; off > 0; off >>= 1) s += __shfl_down(s, off, 64);
    __shared__ float red[4];
    const int lane = t & 63, wv = t >> 6;
    if (lane == 0) red[wv] = s;
    __syncthreads();
    if (t == 0) pooled[bc] = (red[0] + red[1] + red[2] + red[3]) * (1.f / 4096.f);
}

// -------------------------------------------------------------- routing -----
__global__ void cc_routing(const float* __restrict__ pooled,
                           const float* __restrict__ rw_w,
                           const float* __restrict__ rw_b,
                           float* __restrict__ rweights) {
    const int t = threadIdx.x;                 // 256 = 32 b x 8 e
    const int b = t >> 3, e = t & 7;
    const float* p = pooled + b * CC_CIN;
    const float* w = rw_w + e * CC_CIN;
    float acc = rw_b[e];
#pragma unroll 8
    for (int i = 0; i < CC_CIN; ++i) acc += p[i] * w[i];
    float m = acc;
#pragma unroll
    for (int off = 1; off < 8; off <<= 1) m = fmaxf(m, __shfl_xor(m, off, 64));
    const float ex = __expf(acc - m);
    float sum = ex;
#pragma unroll
    for (int off = 1; off < 8; off <<= 1) sum += __shfl_xor(sum, off, 64);
    rweights[t] = ex / sum;
}

// -------------------------------------------------------------- combine -----
// cw[b][t9][cout][cin] (bf16) = sum_e rw[b][e] * EW[e][cout][cin][ky][kx]
__global__ void cc_combine(const float* __restrict__ ew,
                           const float* __restrict__ rw,
                           __hip_bfloat16* __restrict__ cw) {
    const int t9 = blockIdx.x >> 8;            // 0..8
    const int cout = blockIdx.x & 255;
    const int cin = threadIdx.x;               // 128 threads
    __shared__ float rws[256];
    rws[cin] = rw[cin];
    rws[cin + 128] = rw[cin + 128];
    __syncthreads();
    float wv[CC_E];
    const size_t base = ((size_t)cout * CC_CIN + cin) * 9 + t9;
#pragma unroll
    for (int e = 0; e < CC_E; ++e) wv[e] = ew[base + (size_t)e * (CC_COUT * CC_CIN * 9)];
#pragma unroll 4
    for (int b = 0; b < CC_B; ++b) {
        float acc = 0.f;
#pragma unroll
        for (int e = 0; e < CC_E; ++e) acc += rws[b * 8 + e] * wv[e];
        cw[(((size_t)b * 9 + t9) * CC_COUT + cout) * CC_CIN + cin] = __float2bfloat16(acc);
    }
}

// ------------------------------------------------------------ NHWC cast -----
// x[b][cin][y][x] fp32 -> xn[b][y][x][cin] bf16, LDS-tiled per (b,y)
__global__ void cc_nhwc(const float* __restrict__ x, __hip_bfloat16* __restrict__ xn) {
    const int b = blockIdx.x >> 6, y = blockIdx.x & 63;   // 2048 blocks
    __shared__ float lds[64 * 129];                        // [x][cin], +1 pad
    const int t = threadIdx.x;                             // 256
    const float* src = x + (size_t)b * CC_CIN * 4096 + y * 64;
#pragma unroll
    for (int i = 0; i < 32; ++i) {
        const int idx = i * 256 + t;
        const int cin = idx >> 6, xx = idx & 63;
        lds[xx * 129 + cin] = src[(size_t)cin * 4096 + xx];
    }
    __syncthreads();
    __hip_bfloat16* dst = xn + ((size_t)b * 4096 + y * 64) * CC_CIN;
#pragma unroll
    for (int j = 0; j < 4; ++j) {
        const int cidx = j * 256 + t;                      // 1024 chunks of 8 cin
        const int xx = cidx >> 4, c8 = (cidx & 15) * 8;
        union { __hip_bfloat16 h[8]; uint4 v; } u;
#pragma unroll
        for (int jj = 0; jj < 8; ++jj) u.h[jj] = __float2bfloat16(lds[xx * 129 + c8 + jj]);
        *reinterpret_cast<uint4*>(dst + (size_t)xx * CC_CIN + c8) = u.v;
    }
}

// ----------------------------------------------------------------- conv -----
__device__ __forceinline__ void gload_lds16(const void* g, void* l) {
    __builtin_amdgcn_global_load_lds(
        (const __attribute__((address_space(1))) unsigned int*)g,
        (__attribute__((address_space(3))) unsigned int*)l, 16, 0, 0);
}

// grid (61, 2, 32), block 256. Per-block GEMM tile: BM=128 couts x BN=64 pos,
// K = 9*(2x64 cin). A = cw[b][t9] [256][128], B = im2col of xn (NHWC gather).
__global__ __launch_bounds__(256) void cc_conv(
    const __hip_bfloat16* __restrict__ xn,   // [B][64][64][128]
    const __hip_bfloat16* __restrict__ cw,   // [B][9][256][128]
    float* __restrict__ out)                 // [B][256][3844]
{
    const int n0 = blockIdx.x * 64;
    const int m0 = blockIdx.y * 128;
    const int b  = blockIdx.z;
    const int tid = threadIdx.x;
    const int wid = tid >> 6, lane = tid & 63;

    // LDS: linear row-major [row][64 cin] = 128B rows of 8x16B chunks.
    // Swizzle (T2 + rule 21): slot s of row r holds source chunk g = s ^ (r&7).
    __shared__ __hip_bfloat16 Asm[128 * 64];   // 16 KB
    __shared__ __hip_bfloat16 Bsm[64 * 64];    //  8 KB

    f32x4 acc[4][2];
#pragma unroll
    for (int i = 0; i < 4; ++i)
#pragma unroll
        for (int j = 0; j < 2; ++j) acc[i][j] = (f32x4){0.f, 0.f, 0.f, 0.f};

    // staging source-swizzle: row&7 == lane>>3 for every issue
    const int gsw = (lane & 7) ^ (lane >> 3);

    // A staging bases (4 issues/wave, 8 rows each): element offset inside cw[b][t9]
    size_t laBase[4];
#pragma unroll
    for (int i = 0; i < 4; ++i) {
        const int row = wid * 32 + i * 8 + (lane >> 3);
        laBase[i] = (size_t)(m0 + row) * CC_CIN + gsw * 8;
    }
    // B staging bases (2 issues/wave): element offset inside xn[b]
    size_t lbBase[2];
#pragma unroll
    for (int i = 0; i < 2; ++i) {
        const int row = wid * 16 + i * 8 + (lane >> 3);
        int p = n0 + row; if (p > CC_NP - 1) p = CC_NP - 1;      // clamp tail
        const int oy = p / 62, ox = p - oy * 62;
        lbBase[i] = ((size_t)oy * 64 + ox) * CC_CIN + gsw * 8;
    }

    const __hip_bfloat16* cwb = cw + (size_t)b * 9 * CC_COUT * CC_CIN;
    const __hip_bfloat16* xnb = xn + (size_t)b * 4096 * CC_CIN;

    const int mB = (wid >> 1) * 64, nB = (wid & 1) * 32;
    const int rl = lane & 15, gq = lane >> 4, l7 = lane & 7;

    for (int t9 = 0; t9 < 9; ++t9) {
        const int ky = t9 / 3, kx = t9 - ky * 3;
        const __hip_bfloat16* cwt = cwb + (size_t)t9 * CC_COUT * CC_CIN;
        const size_t xoff9 = ((size_t)ky * 64 + kx) * CC_CIN;
#pragma unroll
        for (int kb = 0; kb < 2; ++kb) {
            const size_t ko = (size_t)kb * 64;
            // ---- stage (async, per-lane gathered source, linear LDS dest)
#pragma unroll
            for (int i = 0; i < 4; ++i)
                gload_lds16(cwt + laBase[i] + ko, (char*)Asm + wid * 4096 + i * 1024);
#pragma unroll
            for (int i = 0; i < 2; ++i)
                gload_lds16(xnb + lbBase[i] + xoff9 + ko, (char*)Bsm + wid * 2048 + i * 1024);
            __syncthreads();   // compiler drains vmcnt(0) before barrier
            // ---- compute: 2 k-halves x (4m x 2n) mfma 16x16x32
#pragma unroll
            for (int kk = 0; kk < 2; ++kk) {
                bf16x8 af[4], bfr[2];
#pragma unroll
                for (int mf = 0; mf < 4; ++mf) {
                    const int r = mB + mf * 16 + rl;
                    const int s = (kk * 4 + gq) ^ l7;
                    af[mf] = *(const bf16x8*)((const char*)Asm + r * 128 + s * 16);
                }
#pragma unroll
                for (int nf = 0; nf < 2; ++nf) {
                    const int r = nB + nf * 16 + rl;
                    const int s = (kk * 4 + gq) ^ l7;
                    bfr[nf] = *(const bf16x8*)((const char*)Bsm + r * 128 + s * 16);
                }
#pragma unroll
                for (int mf = 0; mf < 4; ++mf)
#pragma unroll
                    for (int nf = 0; nf < 2; ++nf)
                        acc[mf][nf] = __builtin_amdgcn_mfma_f32_16x16x32_bf16(
                            af[mf], bfr[nf], acc[mf][nf], 0, 0, 0);
            }
            __syncthreads();   // reads done before next stage overwrites
        }
    }

    // ---- epilogue: C/D layout col=lane&15 (p), row=(lane>>4)*4+j (cout)
    const int pcol = n0 + nB + (lane & 15);
    const int crow = m0 + mB + (lane >> 4) * 4;
#pragma unroll
    for (int mf = 0; mf < 4; ++mf) {
#pragma unroll
        for (int nf = 0; nf < 2; ++nf) {
            const int p = pcol + nf * 16;
            if (p < CC_NP) {
                const size_t obase = ((size_t)b * CC_COUT + crow + mf * 16) * CC_NP + p;
#pragma unroll
                for (int jj = 0; jj < 4; ++jj)
                    out[obase + (size_t)jj * CC_NP] = acc[mf][nf][jj];
            }
        }
    }
}

// ---------------------------------------------------------------- launch ----
extern "C" void kernel_launch(void* const* d_in, const int* in_sizes, int n_in,
                              void* d_out, int out_size, void* d_ws, size_t ws_size,
                              hipStream_t stream) {
    const float* x   = (const float*)d_in[0];
    const float* ew  = (const float*)d_in[1];
    const float* rww = (const float*)d_in[2];
    const float* rwb = (const float*)d_in[3];
    float* out = (float*)d_out;
    char* ws = (char*)d_ws;

    __hip_bfloat16* xnhwc = (__hip_bfloat16*)ws;                    // 33,554,432 B
    __hip_bfloat16* cwcmb = (__hip_bfloat16*)(ws + 33554432);       // 18,874,368 B
    float* pooled = (float*)(ws + 52428800);                        //     16,384 B
    float* rwts   = (float*)(ws + 52445184);                        //      1,024 B

    cc_pool<<<dim3(CC_B * CC_CIN), dim3(256), 0, stream>>>(x, pooled);
    cc_routing<<<dim3(1), dim3(256), 0, stream>>>(pooled, rww, rwb, rwts);
    cc_combine<<<dim3(9 * CC_COUT), dim3(128), 0, stream>>>(ew, rwts, cwcmb);
    cc_nhwc<<<dim3(CC_B * CC_H), dim3(256), 0, stream>>>(x, xnhwc);
    cc_conv<<<dim3(61, 2, CC_B), dim3(256), 0, stream>>>(xnhwc, cwcmb, out);
}

// Round 2
// 132.584 us; speedup vs baseline: 1.1781x; 1.1781x over previous
//
#include <hip/hip_runtime.h>
#include <hip/hip_bf16.h>

// CondConv: B=32, CIN=128, COUT=256, K=3, E=8, H=W=64 -> out [32,256,62,62] fp32
// Pipeline: nhwc(+pool partials) -> reduce -> routing -> combine(bf16 cw) ->
//           implicit-GEMM MFMA conv (256x256 tile, dbuf LDS, counted vmcnt).

#define CC_B    32
#define CC_CIN  128
#define CC_COUT 256
#define CC_NP   3844   // 62*62
#define CC_NT   18     // K-tiles: 9 taps x 2 cin-halves of 64

typedef __attribute__((ext_vector_type(8))) short bf16x8;
typedef __attribute__((ext_vector_type(4))) float f32x4;

// ------------------------------------------------- NHWC cast + pool partials
__global__ void cc_nhwc(const float* __restrict__ x, __hip_bfloat16* __restrict__ xn,
                        float* __restrict__ psum) {
    const int b = blockIdx.x >> 6, y = blockIdx.x & 63;   // 2048 blocks
    __shared__ float lds[64 * 129];                        // [x][cin], +1 pad
    __shared__ float sred[256];
    const int t = threadIdx.x;                             // 256
    const float* src = x + (size_t)b * CC_CIN * 4096 + y * 64;
#pragma unroll
    for (int i = 0; i < 32; ++i) {
        const int idx = i * 256 + t;
        const int cin = idx >> 6, xx = idx & 63;
        lds[xx * 129 + cin] = src[(size_t)cin * 4096 + xx];
    }
    __syncthreads();
    __hip_bfloat16* dst = xn + ((size_t)b * 4096 + y * 64) * CC_CIN;
#pragma unroll
    for (int j = 0; j < 4; ++j) {
        const int cidx = j * 256 + t;                      // 1024 chunks of 8 cin
        const int xx = cidx >> 4, c8 = (cidx & 15) * 8;
        union { __hip_bfloat16 h[8]; uint4 v; } u;
#pragma unroll
        for (int jj = 0; jj < 8; ++jj) u.h[jj] = __float2bfloat16(lds[xx * 129 + c8 + jj]);
        *reinterpret_cast<uint4*>(dst + (size_t)xx * CC_CIN + c8) = u.v;
    }
    // pool partial: sum over the 64 x's of this row
    const int cin = t & 127, xh = (t >> 7) * 32;
    float s = 0.f;
#pragma unroll
    for (int xx = 0; xx < 32; ++xx) s += lds[(xh + xx) * 129 + cin];
    sred[t] = s;
    __syncthreads();
    if (t < 128) psum[((size_t)b * 64 + y) * CC_CIN + t] = sred[t] + sred[t + 128];
}

// ----------------------------------------------------------------- reduce --
__global__ void cc_reduce(const float* __restrict__ psum, float* __restrict__ pooled) {
    const int b = blockIdx.x, c = threadIdx.x;             // 32 blocks x 128
    const float* p = psum + (size_t)b * 64 * CC_CIN + c;
    float s = 0.f;
#pragma unroll 8
    for (int y = 0; y < 64; ++y) s += p[(size_t)y * CC_CIN];
    pooled[b * CC_CIN + c] = s * (1.f / 4096.f);
}

// -------------------------------------------------------------- routing -----
__global__ void cc_routing(const float* __restrict__ pooled,
                           const float* __restrict__ rw_w,
                           const float* __restrict__ rw_b,
                           float* __restrict__ rweights) {
    const int t = threadIdx.x;                 // 256 = 32 b x 8 e
    const int b = t >> 3, e = t & 7;
    const float* p = pooled + b * CC_CIN;
    const float* w = rw_w + e * CC_CIN;
    float acc = rw_b[e];
#pragma unroll 8
    for (int i = 0; i < CC_CIN; ++i) acc += p[i] * w[i];
    float m = acc;
#pragma unroll
    for (int off = 1; off < 8; off <<= 1) m = fmaxf(m, __shfl_xor(m, off, 64));
    const float ex = __expf(acc - m);
    float sum = ex;
#pragma unroll
    for (int off = 1; off < 8; off <<= 1) sum += __shfl_xor(sum, off, 64);
    rweights[t] = ex / sum;
}

// -------------------------------------------------------------- combine -----
// cw[b][t9][cout][cin] (bf16) = sum_e rw[b][e] * EW[e][cout][cin][ky][kx]
__global__ void cc_combine(const float* __restrict__ ew,
                           const float* __restrict__ rw,
                           __hip_bfloat16* __restrict__ cw) {
    const int t9 = blockIdx.x >> 8;            // 0..8
    const int cout = blockIdx.x & 255;
    const int cin = threadIdx.x;               // 128 threads
    __shared__ float rws[256];
    rws[cin] = rw[cin];
    rws[cin + 128] = rw[cin + 128];
    __syncthreads();
    float wv[8];
    const size_t base = ((size_t)cout * CC_CIN + cin) * 9 + t9;
#pragma unroll
    for (int e = 0; e < 8; ++e) wv[e] = ew[base + (size_t)e * (CC_COUT * CC_CIN * 9)];
#pragma unroll 4
    for (int b = 0; b < CC_B; ++b) {
        float acc = 0.f;
#pragma unroll
        for (int e = 0; e < 8; ++e) acc += rws[b * 8 + e] * wv[e];
        cw[(((size_t)b * 9 + t9) * CC_COUT + cout) * CC_CIN + cin] = __float2bfloat16(acc);
    }
}

// ----------------------------------------------------------------- conv -----
__device__ __forceinline__ void gload_lds16(const void* g, void* l) {
    __builtin_amdgcn_global_load_lds(
        (const __attribute__((address_space(1))) unsigned int*)g,
        (__attribute__((address_space(3))) unsigned int*)l, 16, 0, 0);
}

// grid (16, 32), block 512 (8 waves, 2M x 4N). Tile BM=256 couts x BN=256 pos,
// BK=64. LDS 128KB: A dbuf 2x32KB @0, B dbuf 2x32KB @64KB. K-tile t in buf[t&1].
// Counted vmcnt: stage(t+2) issued after closing barrier of iter t; opening
// wait = vmcnt(8) (stage(t+1) still in flight). Swizzle: slot s of 128B row r
// holds source chunk s ^ (r&7) (linear global_load_lds dest, pre-swz source).
__global__ __launch_bounds__(512, 2) void cc_conv(
    const __hip_bfloat16* __restrict__ xn,   // [B][64][64][128]
    const __hip_bfloat16* __restrict__ cw,   // [B][9][256][128]
    float* __restrict__ out)                 // [B][256][3844]
{
    __shared__ __align__(16) char smem[131072];
    const int n0 = blockIdx.x * 256;
    const int b  = blockIdx.y;
    const int tid = threadIdx.x;
    const int wid = tid >> 6, lane = tid & 63;
    const int waveM = wid >> 2, waveN = wid & 3;

    f32x4 acc[8][4];
#pragma unroll
    for (int i = 0; i < 8; ++i)
#pragma unroll
        for (int j = 0; j < 4; ++j) acc[i][j] = (f32x4){0.f, 0.f, 0.f, 0.f};

    // staging: wave w, issue i covers rows w*32+i*8 .. +7; lane -> row l>>3,
    // slot l&7; source chunk pre-swizzled so slot s of row r holds chunk s^(r&7)
    const int gsw = (lane & 7) ^ (lane >> 3);
    int laOff[4], lbOff[4];
#pragma unroll
    for (int i = 0; i < 4; ++i) {
        const int row = wid * 32 + i * 8 + (lane >> 3);
        laOff[i] = row * CC_CIN + gsw * 8;
        int p = n0 + row; if (p > CC_NP - 1) p = CC_NP - 1;   // tail clamp
        const int oy = p / 62, ox = p - oy * 62;
        lbOff[i] = (oy * 64 + ox) * CC_CIN + gsw * 8;
    }

    const __hip_bfloat16* cwb = cw + (size_t)b * 9 * CC_COUT * CC_CIN;
    const __hip_bfloat16* xnb = xn + (size_t)b * 4096 * CC_CIN;

    auto stageK = [&](int t) {
        const int t9 = t >> 1;
        const int ky = (t9 * 11) >> 5;          // t9/3 for t9<9
        const int kx = t9 - ky * 3;
        const int aoff = t9 * (CC_COUT * CC_CIN) + (t & 1) * 64;
        const int boff = (ky * 64 + kx) * CC_CIN + (t & 1) * 64;
        char* Ab = smem + (t & 1) * 32768 + wid * 4096;
        char* Bb = smem + 65536 + (t & 1) * 32768 + wid * 4096;
#pragma unroll
        for (int i = 0; i < 4; ++i)
            gload_lds16(cwb + aoff + laOff[i], Ab + i * 1024);
#pragma unroll
        for (int i = 0; i < 4; ++i)
            gload_lds16(xnb + boff + lbOff[i], Bb + i * 1024);
    };

    const int rl = lane & 15, q = lane >> 4;
    auto computeK = [&](int t) {
        const char* Ab = smem + (t & 1) * 32768;
        const char* Bb = smem + 65536 + (t & 1) * 32768;
#pragma unroll
        for (int kk = 0; kk < 2; ++kk) {
            bf16x8 af[8], bfr[4];
#pragma unroll
            for (int mf = 0; mf < 8; ++mf) {
                const int r = waveM * 128 + mf * 16 + rl;
                af[mf] = *(const bf16x8*)(Ab + r * 128 + (((kk * 4 + q) ^ (r & 7)) * 16));
            }
#pragma unroll
            for (int nf = 0; nf < 4; ++nf) {
                const int r = waveN * 64 + nf * 16 + rl;
                bfr[nf] = *(const bf16x8*)(Bb + r * 128 + (((kk * 4 + q) ^ (r & 7)) * 16));
            }
#pragma unroll
            for (int mf = 0; mf < 8; ++mf)
#pragma unroll
                for (int nf = 0; nf < 4; ++nf)
                    acc[mf][nf] = __builtin_amdgcn_mfma_f32_16x16x32_bf16(
                        af[mf], bfr[nf], acc[mf][nf], 0, 0, 0);
        }
    };

    // prologue: 2 K-tiles in flight
    stageK(0);
    stageK(1);

#pragma unroll 1
    for (int t = 0; t < CC_NT - 1; ++t) {
        // slot (t&1) ready when its 8 loads retired; stage(t+1)'s 8 may remain
        asm volatile("s_waitcnt vmcnt(8)\n\ts_barrier" ::: "memory");
        computeK(t);
        // all LDS reads returned before anyone overwrites buf[t&1]
        asm volatile("s_waitcnt lgkmcnt(0)\n\ts_barrier" ::: "memory");
        if (t + 2 < CC_NT) stageK(t + 2);
    }
    asm volatile("s_waitcnt vmcnt(0)\n\ts_barrier" ::: "memory");
    computeK(CC_NT - 1);

    // epilogue: C/D map col=lane&15 (p), row=(lane>>4)*4+j (cout)
    const int q4 = (lane >> 4) * 4;
#pragma unroll
    for (int mf = 0; mf < 8; ++mf) {
        const int crow = waveM * 128 + mf * 16 + q4;
#pragma unroll
        for (int nf = 0; nf < 4; ++nf) {
            const int p = n0 + waveN * 64 + nf * 16 + (lane & 15);
            if (p < CC_NP) {
                const size_t ob = ((size_t)b * CC_COUT + crow) * CC_NP + p;
#pragma unroll
                for (int j = 0; j < 4; ++j) out[ob + (size_t)j * CC_NP] = acc[mf][nf][j];
            }
        }
    }
}

// ---------------------------------------------------------------- launch ----
extern "C" void kernel_launch(void* const* d_in, const int* in_sizes, int n_in,
                              void* d_out, int out_size, void* d_ws, size_t ws_size,
                              hipStream_t stream) {
    const float* x   = (const float*)d_in[0];
    const float* ew  = (const float*)d_in[1];
    const float* rww = (const float*)d_in[2];
    const float* rwb = (const float*)d_in[3];
    float* out = (float*)d_out;
    char* ws = (char*)d_ws;

    __hip_bfloat16* xnhwc = (__hip_bfloat16*)ws;                    // 33,554,432 B
    __hip_bfloat16* cwcmb = (__hip_bfloat16*)(ws + 33554432);       // 18,874,368 B
    float* psum   = (float*)(ws + 52428800);                        //  1,048,576 B
    float* pooled = (float*)(ws + 53477376);                        //     16,384 B
    float* rwts   = (float*)(ws + 53493760);                        //      1,024 B

    cc_nhwc<<<dim3(CC_B * 64), dim3(256), 0, stream>>>(x, xnhwc, psum);
    cc_reduce<<<dim3(CC_B), dim3(128), 0, stream>>>(psum, pooled);
    cc_routing<<<dim3(1), dim3(256), 0, stream>>>(pooled, rww, rwb, rwts);
    cc_combine<<<dim3(9 * CC_COUT), dim3(128), 0, stream>>>(ew, rwts, cwcmb);
    cc_conv<<<dim3(16, CC_B), dim3(512), 0, stream>>>(xnhwc, cwcmb, out);
}